// Round 1
// baseline (634.168 us; speedup 1.0000x reference)
//
#include <hip/hip_runtime.h>
#include <math.h>

// Problem constants (from reference)
#define BB 4
#define TT 2048
#define CC 48
#define DD 512
#define LL 16
#define NTR 15
#define NCAND 45
#define WINLEN 19   // int(T/L*0.15)
#define CSW 15
#define CCHALF 7

static __device__ __forceinline__ float wave_reduce_sum(float v) {
    for (int off = 32; off; off >>= 1) v += __shfl_down(v, off);
    return v;
}

// ---------------- Kernel 1: row softmax / log-softmax ----------------
__global__ __launch_bounds__(64) void k_softmax(const float* __restrict__ fr,
                                                float* __restrict__ prob,
                                                float* __restrict__ logp,
                                                float* __restrict__ lse) {
    int row = blockIdx.x;                 // b*T + t
    int c = threadIdx.x;
    const float* x = fr + (size_t)row * CC;
    float xv = (c < CC) ? x[c] : -INFINITY;
    float m = xv;
    for (int off = 32; off; off >>= 1) m = fmaxf(m, __shfl_down(m, off));
    m = __shfl(m, 0);
    float e = (c < CC) ? expf(xv - m) : 0.f;
    float s = wave_reduce_sum(e);
    s = __shfl(s, 0);
    if (c < CC) {
        float p = e / s;
        prob[(size_t)row * CC + c] = p;
        logp[(size_t)row * CC + c] = logf(p);
    }
    if (c == 0) lse[row] = m + logf(s);
}

// ---------------- Kernel 2: boundary (JS) score ----------------
// score[t] = -2/(81*ln2) * sum_{i<j} KER[i,j]*(kl[i,j]+kl[j,i])
__global__ __launch_bounds__(64) void k_score(const float* __restrict__ prob,
                                              const float* __restrict__ logp,
                                              float* __restrict__ score) {
    int row = blockIdx.x;
    int b = row / TT, t = row % TT;
    __shared__ float sp[9][CC];
    __shared__ float slp[9][CC];
    int tid = threadIdx.x;
    for (int idx = tid; idx < 9 * CC; idx += 64) {
        int i = idx / CC, c = idx - (idx / CC) * CC;
        int r = t - 4 + i;
        float pv = 0.f, lv = 0.f;
        if (r >= 0 && r < TT) {
            pv = prob[((size_t)b * TT + r) * CC + c];
            lv = logp[((size_t)b * TT + r) * CC + c];
        }
        sp[i][c] = pv;
        slp[i][c] = lv;
    }
    __syncthreads();
    float acc = 0.f;
    for (int item = tid; item < 36 * CC; item += 64) {
        int pidx = item / CC, c = item - pidx * CC;
        int i = 0, rem = pidx;
        while (rem >= 8 - i) { rem -= 8 - i; ++i; }
        int j = i + 1 + rem;
        float wgt = ((i < 4) == (j < 4)) ? 1.f : -1.f;
        float pi = sp[i][c], pj = sp[j][c];
        float logm = logf(0.5f * (pi + pj) + 1e-32f);
        float term = 0.f;
        if (pi > 0.f) term += pi * (slp[i][c] - logm);
        if (pj > 0.f) term += pj * (slp[j][c] - logm);
        acc += wgt * term;
    }
    acc = wave_reduce_sum(acc);
    if (tid == 0) {
        const float SC = -2.0f / (81.0f * 0.6931471805599453f);
        score[row] = (t == 0) ? -INFINITY : SC * acc;
    }
}

// ---------------- Kernel 3: greedy candidate pick + sort ----------------
__global__ __launch_bounds__(256) void k_pick(const float* __restrict__ score,
                                              int* __restrict__ cand) {
    int b = blockIdx.x;
    __shared__ float s[TT];
    __shared__ float rv[256];
    __shared__ int ri[256];
    __shared__ int cl[NCAND];
    int tid = threadIdx.x;
    for (int t = tid; t < TT; t += 256) s[t] = score[(size_t)b * TT + t];
    __syncthreads();
    for (int it = 0; it < NCAND; ++it) {
        float bv = -INFINITY;
        int bi = 0x7fffffff;
        for (int t = tid; t < TT; t += 256) {
            float v = s[t];
            if (v > bv) { bv = v; bi = t; }   // strict > keeps first index
        }
        rv[tid] = bv; ri[tid] = bi;
        __syncthreads();
        for (int off = 128; off; off >>= 1) {
            if (tid < off) {
                float v2 = rv[tid + off]; int i2 = ri[tid + off];
                if (v2 > rv[tid] || (v2 == rv[tid] && i2 < ri[tid])) { rv[tid] = v2; ri[tid] = i2; }
            }
            __syncthreads();
        }
        int imax = ri[0];
        if (tid == 0) cl[it] = imax;
        int lo = imax - WINLEN; if (lo < 0) lo = 0;
        int hi = imax + WINLEN; if (hi > TT - 1) hi = TT - 1;
        for (int t = lo + tid; t <= hi; t += 256) s[t] = -INFINITY;
        __syncthreads();
    }
    if (tid == 0) {
        for (int a = 1; a < NCAND; ++a) {
            int key = cl[a]; int b2 = a - 1;
            while (b2 >= 0 && cl[b2] > key) { cl[b2 + 1] = cl[b2]; --b2; }
            cl[b2 + 1] = key;
        }
        for (int a = 0; a < NCAND; ++a) cand[b * 64 + a] = cl[a];
    }
}

// ---------------- Kernel 4: cls + DP + backtrack + pse + labels ----------------
__global__ __launch_bounds__(256) void k_dp(const float* __restrict__ prob,
                                            const float* __restrict__ score,
                                            const int* __restrict__ cand,
                                            const int* __restrict__ transcript,
                                            int* __restrict__ labels_out,
                                            int* __restrict__ pse) {
    int b = blockIdx.x;
    __shared__ float cost[NTR][NCAND];
    __shared__ int tr_s[LL];
    __shared__ int cand_s[NCAND];
    __shared__ float backup_s[NCAND];
    __shared__ signed char dir_mat[NCAND][32];
    __shared__ int bdy_s[NTR];
    int tid = threadIdx.x;
    if (tid < LL) tr_s[tid] = transcript[b * LL + tid];
    if (tid < NCAND) {
        int cp = cand[b * 64 + tid];
        cand_s[tid] = cp;
        backup_s[tid] = score[(size_t)b * TT + cp];
    }
    __syncthreads();
    // cls matrix -> cost = -(conv/30 + backup)
    for (int e = tid; e < NTR * NCAND; e += 256) {
        int j = e / NCAND, ii = e - (e / NCAND) * NCAND;
        int cpos = cand_s[ii];
        int trj = tr_s[j], trj1 = tr_s[j + 1];
        float sum = 0.f;
        for (int k = 0; k < CSW; ++k) {
            int r = cpos - CCHALF + k;
            float a = 0.f, d2 = 0.f;
            if (r >= 0 && r < TT) {
                const float* pr = prob + ((size_t)b * TT + r) * CC;
                a = pr[trj]; d2 = pr[trj1];
            }
            sum += ((k < CCHALF) ? 1.f : -1.f) * (a - d2);
        }
        cost[j][ii] = -(sum / 30.f + backup_s[ii]);
    }
    __syncthreads();
    // DP on wave 0: state j = lane j (W = 31 states)
    if (tid < 64) {
        int lane = tid;
        float prev = INFINITY;
        if (lane == 0) prev = 0.f;              // ii=0 < 30
        if (lane == 1) prev = cost[0][0];
        if (lane < 31) dir_mat[0][lane] = (lane == 1) ? (signed char)1 : (signed char)0;
        for (int ii = 1; ii < NCAND; ++ii) {
            float dm1 = __shfl_up(prev, 1); if (lane < 1) dm1 = INFINITY;
            float dm2 = __shfl_up(prev, 2); if (lane < 2) dm2 = INFINITY;
            int trat = lane >> 1; if (trat > NTR - 1) trat = NTR - 1;
            float c_at = cost[trat][ii];
            float ev = fminf(prev, dm1);
            int ed = (prev < dm1) ? 0 : 1;
            float ov = c_at + fminf(dm1, dm2);
            int od = (dm1 < dm2) ? 1 : 2;
            float nv; int nd;
            if (lane >= 2) {
                if ((lane & 1) == 0) { nv = ev; nd = ed; }
                else { nv = ov; nd = od; }
            } else { nv = INFINITY; nd = 0; }
            if (lane == 0) { nv = (ii < NCAND - NTR) ? 0.f : INFINITY; nd = 0; }
            if (lane == 1) {
                nv = (ii <= NCAND - NTR) ? cost[0][ii] : INFINITY;
                nd = (ii <= NCAND - NTR) ? 1 : 0;
            }
            prev = nv;
            if (lane < 31) dir_mat[ii][lane] = (signed char)nd;
        }
        float v29 = __shfl(prev, 29);
        float v30 = __shfl(prev, 30);
        if (lane == 0) {
            int cur = (v30 < v29) ? 30 : 29;
            for (int ii = NCAND - 1; ii >= 0; --ii) {
                if (cur & 1) bdy_s[cur >> 1] = cand_s[ii];
                cur -= (int)dir_mat[ii][cur];
            }
            // sorted labels
            int lab[LL];
            for (int i2 = 0; i2 < LL; ++i2) lab[i2] = tr_s[i2];
            for (int a2 = 1; a2 < LL; ++a2) {
                int key = lab[a2]; int b2 = a2 - 1;
                while (b2 >= 0 && lab[b2] > key) { lab[b2 + 1] = lab[b2]; --b2; }
                lab[b2 + 1] = key;
            }
            for (int i2 = 0; i2 < LL; ++i2) labels_out[b * LL + i2] = lab[i2];
        }
    }
    __syncthreads();
    // pse[t] = tr[#boundaries <= t]
    for (int t = tid; t < TT; t += 256) {
        int cnt = 0;
        for (int j = 0; j < NTR; ++j) cnt += (t >= bdy_s[j]) ? 1 : 0;
        pse[b * TT + t] = tr_s[cnt];
    }
}

// ---------------- Kernel 5: segment feature sums (oh @ fr) ----------------
__global__ __launch_bounds__(256) void k_la(const float* __restrict__ feat,
                                            const int* __restrict__ pse,
                                            const int* __restrict__ labels,
                                            float* __restrict__ la) {
    int l = blockIdx.x, b = blockIdx.y;
    int lab = labels[b * LL + l];
    const float* fr = feat + ((size_t)b * (CC + TT) + CC) * DD;
    int tid = threadIdx.x;
    __shared__ int ps[TT];
    for (int t = tid; t < TT; t += 256) ps[t] = pse[b * TT + t];
    __syncthreads();
    float a0 = 0.f, a1 = 0.f;
    for (int t = 0; t < TT; ++t) {
        if (ps[t] == lab) {
            const float* r = fr + (size_t)t * DD;
            a0 += r[tid];
            a1 += r[tid + 256];
        }
    }
    float* lar = la + ((size_t)b * LL + l) * DD;
    lar[tid] = a0;          // raw sum; /cnt cancels under normalization
    lar[tid + 256] = a1;
}

// ---------------- Kernel 6: final fusion ----------------
__global__ __launch_bounds__(256) void k_final(const float* __restrict__ tok_logit,
                                               const float* __restrict__ fr_logit,
                                               const float* __restrict__ vid,
                                               const float* __restrict__ feat,
                                               const float* __restrict__ lse,
                                               const int* __restrict__ pse,
                                               const int* __restrict__ labels,
                                               const float* __restrict__ la,
                                               float* __restrict__ out) {
    int tid = threadIdx.x;
    __shared__ float red[4];
    __shared__ float s_tok, s_fr;
    __shared__ float nla[BB * LL];
    __shared__ float ntk[BB * CC];
    __shared__ float la_s[LL * DD];     // 32 KB
    __shared__ float sim_s[LL * CC];
    __shared__ float term_s[LL];
    __shared__ float batch_term[BB];

    // tok_loss (BCE with logits)
    float acc = 0.f;
    for (int i = tid; i < BB * CC; i += 256) {
        float x = tok_logit[i], y = vid[i];
        float lsp = fminf(x, 0.f) - log1pf(expf(-fabsf(x)));    // log_sigmoid(x)
        float lsn = fminf(-x, 0.f) - log1pf(expf(-fabsf(x)));   // log_sigmoid(-x)
        acc += -(y * lsp + (1.f - y) * lsn);
    }
    float w = wave_reduce_sum(acc);
    if ((tid & 63) == 0) red[tid >> 6] = w;
    __syncthreads();
    if (tid == 0) s_tok = (red[0] + red[1] + red[2] + red[3]) / (float)(BB * CC);
    __syncthreads();

    // fr_loss (mask all-ones)
    acc = 0.f;
    for (int i = tid; i < BB * TT; i += 256) {
        int p = pse[i];
        acc += lse[i] - fr_logit[(size_t)i * CC + p];
    }
    w = wave_reduce_sum(acc);
    if ((tid & 63) == 0) red[tid >> 6] = w;
    __syncthreads();
    if (tid == 0) s_fr = (red[0] + red[1] + red[2] + red[3]) / (float)(BB * TT);
    __syncthreads();

    // norms: 64 la rows + 192 tok rows = 256 rows, one per thread
    {
        const float* rowp;
        if (tid < BB * LL) rowp = la + (size_t)tid * DD;
        else {
            int k = tid - BB * LL;
            int b = k / CC, c = k - (k / CC) * CC;
            rowp = feat + ((size_t)b * (CC + TT) + c) * DD;
        }
        float ss = 0.f;
        for (int d = 0; d < DD; ++d) { float v = rowp[d]; ss += v * v; }
        float nn = fmaxf(sqrtf(ss), 1e-12f);
        if (tid < BB * LL) nla[tid] = nn; else ntk[tid - BB * LL] = nn;
    }
    __syncthreads();

    // glc per batch
    for (int b = 0; b < BB; ++b) {
        for (int i = tid; i < LL * DD; i += 256) la_s[i] = la[(size_t)b * LL * DD + i];
        __syncthreads();
        for (int e = tid; e < LL * CC; e += 256) {
            int l = e / CC, c = e - (e / CC) * CC;
            const float* tr = feat + ((size_t)b * (CC + TT) + c) * DD;
            const float* lr = la_s + l * DD;
            float dot = 0.f;
            for (int d = 0; d < DD; ++d) dot += lr[d] * tr[d];
            sim_s[e] = dot / (nla[b * LL + l] * ntk[b * CC + c]) * 10.0f;  // /TEMP
        }
        __syncthreads();
        if (tid < LL) {
            int l = tid;
            float mx = -INFINITY;
            for (int c = 0; c < CC; ++c) mx = fmaxf(mx, sim_s[l * CC + c]);
            float se = 0.f;
            for (int c = 0; c < CC; ++c) se += expf(sim_s[l * CC + c] - mx);
            int lab = labels[b * LL + l];
            term_s[l] = (mx + logf(se)) - sim_s[l * CC + lab];
        }
        __syncthreads();
        if (tid == 0) {
            float tsum = 0.f;
            for (int l = 0; l < LL; ++l) tsum += term_s[l];
            batch_term[b] = tsum / (float)LL;
        }
        __syncthreads();
    }
    if (tid == 0) {
        float glc = (batch_term[0] + batch_term[1] + batch_term[2] + batch_term[3]) / (float)BB;
        out[0] = s_tok + s_fr + 0.1f * glc;
    }
}

extern "C" void kernel_launch(void* const* d_in, const int* in_sizes, int n_in,
                              void* d_out, int out_size, void* d_ws, size_t ws_size,
                              hipStream_t stream) {
    (void)in_sizes; (void)n_in; (void)out_size; (void)ws_size;
    // input order: epoch, tok_logit, fr_logit, mask, transcript, vid_multi_hot, feat
    const float* tok_logit  = (const float*)d_in[1];
    const float* fr_logit   = (const float*)d_in[2];
    const int*   transcript = (const int*)d_in[4];
    const float* vid        = (const float*)d_in[5];
    const float* feat       = (const float*)d_in[6];
    // mask is all-ones (jnp.ones) -> folded into constants; epoch unused.

    char* ws = (char*)d_ws;
    // workspace layout (bytes); total ~3.38 MB
    float* prob   = (float*)(ws + 0);          // B*T*C
    float* logp   = (float*)(ws + 1572864);    // B*T*C
    float* lse    = (float*)(ws + 3145728);    // B*T
    float* score  = (float*)(ws + 3178496);    // B*T
    float* la     = (float*)(ws + 3211264);    // B*L*D
    int*   cand   = (int*)(ws + 3342336);      // B*64
    int*   labels = (int*)(ws + 3343360);      // B*L
    int*   pse    = (int*)(ws + 3343616);      // B*T
    float* out    = (float*)d_out;

    k_softmax<<<BB * TT, 64, 0, stream>>>(fr_logit, prob, logp, lse);
    k_score<<<BB * TT, 64, 0, stream>>>(prob, logp, score);
    k_pick<<<BB, 256, 0, stream>>>(score, cand);
    k_dp<<<BB, 256, 0, stream>>>(prob, score, cand, transcript, labels, pse);
    k_la<<<dim3(LL, BB), 256, 0, stream>>>(feat, pse, labels, la);
    k_final<<<1, 256, 0, stream>>>(tok_logit, fr_logit, vid, feat, lse, pse, labels, la, out);
}

// Round 2
// 430.913 us; speedup vs baseline: 1.4717x; 1.4717x over previous
//
#include <hip/hip_runtime.h>
#include <math.h>

// Problem constants (from reference)
#define BB 4
#define TT 2048
#define CC 48
#define DD 512
#define LL 16
#define NTR 15
#define NCAND 45
#define WINLEN 19   // int(T/L*0.15)
#define CSW 15
#define CCHALF 7

static __device__ __forceinline__ float wave_reduce_sum(float v) {
    for (int off = 32; off; off >>= 1) v += __shfl_down(v, off);
    return v;
}

// ---------------- Kernel 1: row softmax / log-softmax ----------------
__global__ __launch_bounds__(64) void k_softmax(const float* __restrict__ fr,
                                                float* __restrict__ prob,
                                                float* __restrict__ logp,
                                                float* __restrict__ lse) {
    int row = blockIdx.x;                 // b*T + t
    int c = threadIdx.x;
    const float* x = fr + (size_t)row * CC;
    float xv = (c < CC) ? x[c] : -INFINITY;
    float m = xv;
    for (int off = 32; off; off >>= 1) m = fmaxf(m, __shfl_down(m, off));
    m = __shfl(m, 0);
    float e = (c < CC) ? expf(xv - m) : 0.f;
    float s = wave_reduce_sum(e);
    s = __shfl(s, 0);
    if (c < CC) {
        float p = e / s;
        prob[(size_t)row * CC + c] = p;
        logp[(size_t)row * CC + c] = logf(p);
    }
    if (c == 0) lse[row] = m + logf(s);
}

// ---------------- Kernel 2: boundary (JS) score ----------------
// score[t] = -2/(81*ln2) * sum_{i<j} KER[i,j]*(kl[i,j]+kl[j,i])
__global__ __launch_bounds__(64) void k_score(const float* __restrict__ prob,
                                              const float* __restrict__ logp,
                                              float* __restrict__ score) {
    int row = blockIdx.x;
    int b = row / TT, t = row % TT;
    __shared__ float sp[9][CC];
    __shared__ float slp[9][CC];
    int tid = threadIdx.x;
    for (int idx = tid; idx < 9 * CC; idx += 64) {
        int i = idx / CC, c = idx - (idx / CC) * CC;
        int r = t - 4 + i;
        float pv = 0.f, lv = 0.f;
        if (r >= 0 && r < TT) {
            pv = prob[((size_t)b * TT + r) * CC + c];
            lv = logp[((size_t)b * TT + r) * CC + c];
        }
        sp[i][c] = pv;
        slp[i][c] = lv;
    }
    __syncthreads();
    float acc = 0.f;
    for (int item = tid; item < 36 * CC; item += 64) {
        int pidx = item / CC, c = item - pidx * CC;
        int i = 0, rem = pidx;
        while (rem >= 8 - i) { rem -= 8 - i; ++i; }
        int j = i + 1 + rem;
        float wgt = ((i < 4) == (j < 4)) ? 1.f : -1.f;
        float pi = sp[i][c], pj = sp[j][c];
        float logm = logf(0.5f * (pi + pj) + 1e-32f);
        float term = 0.f;
        if (pi > 0.f) term += pi * (slp[i][c] - logm);
        if (pj > 0.f) term += pj * (slp[j][c] - logm);
        acc += wgt * term;
    }
    acc = wave_reduce_sum(acc);
    if (tid == 0) {
        const float SC = -2.0f / (81.0f * 0.6931471805599453f);
        score[row] = (t == 0) ? -INFINITY : SC * acc;
    }
}

// ---------------- Kernel 3: greedy candidate pick + sort ----------------
__global__ __launch_bounds__(256) void k_pick(const float* __restrict__ score,
                                              int* __restrict__ cand) {
    int b = blockIdx.x;
    __shared__ float s[TT];
    __shared__ float rv[256];
    __shared__ int ri[256];
    __shared__ int cl[NCAND];
    int tid = threadIdx.x;
    for (int t = tid; t < TT; t += 256) s[t] = score[(size_t)b * TT + t];
    __syncthreads();
    for (int it = 0; it < NCAND; ++it) {
        float bv = -INFINITY;
        int bi = 0x7fffffff;
        for (int t = tid; t < TT; t += 256) {
            float v = s[t];
            if (v > bv) { bv = v; bi = t; }   // strict > keeps first index
        }
        rv[tid] = bv; ri[tid] = bi;
        __syncthreads();
        for (int off = 128; off; off >>= 1) {
            if (tid < off) {
                float v2 = rv[tid + off]; int i2 = ri[tid + off];
                if (v2 > rv[tid] || (v2 == rv[tid] && i2 < ri[tid])) { rv[tid] = v2; ri[tid] = i2; }
            }
            __syncthreads();
        }
        int imax = ri[0];
        if (tid == 0) cl[it] = imax;
        int lo = imax - WINLEN; if (lo < 0) lo = 0;
        int hi = imax + WINLEN; if (hi > TT - 1) hi = TT - 1;
        for (int t = lo + tid; t <= hi; t += 256) s[t] = -INFINITY;
        __syncthreads();
    }
    if (tid == 0) {
        for (int a = 1; a < NCAND; ++a) {
            int key = cl[a]; int b2 = a - 1;
            while (b2 >= 0 && cl[b2] > key) { cl[b2 + 1] = cl[b2]; --b2; }
            cl[b2 + 1] = key;
        }
        for (int a = 0; a < NCAND; ++a) cand[b * 64 + a] = cl[a];
    }
}

// ---------------- Kernel 4: cls + DP + backtrack + pse/rowmap + labels ----------------
__global__ __launch_bounds__(256) void k_dp(const float* __restrict__ prob,
                                            const float* __restrict__ score,
                                            const int* __restrict__ cand,
                                            const int* __restrict__ transcript,
                                            int* __restrict__ labels_out,
                                            int* __restrict__ pse,
                                            int* __restrict__ rowmap) {
    int b = blockIdx.x;
    __shared__ float cost[NTR][NCAND];
    __shared__ int tr_s[LL];
    __shared__ int cand_s[NCAND];
    __shared__ float backup_s[NCAND];
    __shared__ signed char dir_mat[NCAND][32];
    __shared__ int bdy_s[NTR];
    __shared__ int rank_s[LL];
    int tid = threadIdx.x;
    if (tid < LL) tr_s[tid] = transcript[b * LL + tid];
    if (tid < NCAND) {
        int cp = cand[b * 64 + tid];
        cand_s[tid] = cp;
        backup_s[tid] = score[(size_t)b * TT + cp];
    }
    __syncthreads();
    // cls matrix -> cost = -(conv/30 + backup)
    for (int e = tid; e < NTR * NCAND; e += 256) {
        int j = e / NCAND, ii = e - (e / NCAND) * NCAND;
        int cpos = cand_s[ii];
        int trj = tr_s[j], trj1 = tr_s[j + 1];
        float sum = 0.f;
        for (int k = 0; k < CSW; ++k) {
            int r = cpos - CCHALF + k;
            float a = 0.f, d2 = 0.f;
            if (r >= 0 && r < TT) {
                const float* pr = prob + ((size_t)b * TT + r) * CC;
                a = pr[trj]; d2 = pr[trj1];
            }
            sum += ((k < CCHALF) ? 1.f : -1.f) * (a - d2);
        }
        cost[j][ii] = -(sum / 30.f + backup_s[ii]);
    }
    __syncthreads();
    // DP on wave 0: state j = lane j (W = 31 states)
    if (tid < 64) {
        int lane = tid;
        float prev = INFINITY;
        if (lane == 0) prev = 0.f;              // ii=0 < 30
        if (lane == 1) prev = cost[0][0];
        if (lane < 31) dir_mat[0][lane] = (lane == 1) ? (signed char)1 : (signed char)0;
        for (int ii = 1; ii < NCAND; ++ii) {
            float dm1 = __shfl_up(prev, 1); if (lane < 1) dm1 = INFINITY;
            float dm2 = __shfl_up(prev, 2); if (lane < 2) dm2 = INFINITY;
            int trat = lane >> 1; if (trat > NTR - 1) trat = NTR - 1;
            float c_at = cost[trat][ii];
            float ev = fminf(prev, dm1);
            int ed = (prev < dm1) ? 0 : 1;
            float ov = c_at + fminf(dm1, dm2);
            int od = (dm1 < dm2) ? 1 : 2;
            float nv; int nd;
            if (lane >= 2) {
                if ((lane & 1) == 0) { nv = ev; nd = ed; }
                else { nv = ov; nd = od; }
            } else { nv = INFINITY; nd = 0; }
            if (lane == 0) { nv = (ii < NCAND - NTR) ? 0.f : INFINITY; nd = 0; }
            if (lane == 1) {
                nv = (ii <= NCAND - NTR) ? cost[0][ii] : INFINITY;
                nd = (ii <= NCAND - NTR) ? 1 : 0;
            }
            prev = nv;
            if (lane < 31) dir_mat[ii][lane] = (signed char)nd;
        }
        float v29 = __shfl(prev, 29);
        float v30 = __shfl(prev, 30);
        if (lane == 0) {
            int cur = (v30 < v29) ? 30 : 29;
            for (int ii = NCAND - 1; ii >= 0; --ii) {
                if (cur & 1) bdy_s[cur >> 1] = cand_s[ii];
                cur -= (int)dir_mat[ii][cur];
            }
            // sorted labels + rank of tr[j] among sorted labels
            int lab[LL];
            for (int i2 = 0; i2 < LL; ++i2) lab[i2] = tr_s[i2];
            for (int a2 = 1; a2 < LL; ++a2) {
                int key = lab[a2]; int b2 = a2 - 1;
                while (b2 >= 0 && lab[b2] > key) { lab[b2 + 1] = lab[b2]; --b2; }
                lab[b2 + 1] = key;
            }
            for (int i2 = 0; i2 < LL; ++i2) labels_out[b * LL + i2] = lab[i2];
            for (int j2 = 0; j2 < LL; ++j2) {
                int r2 = 0;
                for (int l2 = 0; l2 < LL; ++l2) if (lab[l2] == tr_s[j2]) r2 = l2;
                rank_s[j2] = r2;
            }
        }
    }
    __syncthreads();
    // pse[t] = tr[#boundaries <= t]; rowmap[t] = rank (la row) of that tr index
    for (int t = tid; t < TT; t += 256) {
        int cnt = 0;
        for (int j = 0; j < NTR; ++j) cnt += (t >= bdy_s[j]) ? 1 : 0;
        pse[b * TT + t] = tr_s[cnt];
        rowmap[b * TT + t] = rank_s[cnt];
    }
}

// ---------------- Kernel 5: segment feature sums (oh @ fr), tile-scatter ----------------
// grid: (TT/32, BB), 256 threads; each thread owns a float2 column pair.
// rowmap is monotone within a tile -> <= few register flushes via atomicAdd.
__global__ __launch_bounds__(256) void k_la(const float* __restrict__ feat,
                                            const int* __restrict__ rowmap,
                                            float* __restrict__ la) {
    int b = blockIdx.y;
    int t0 = blockIdx.x * 32;
    int tid = threadIdx.x;
    const float* fr = feat + ((size_t)b * (CC + TT) + CC) * DD;
    __shared__ int rm[32];
    if (tid < 32) rm[tid] = rowmap[b * TT + t0 + tid];
    __syncthreads();
    float ax = 0.f, ay = 0.f;
    int cur = rm[0];
    for (int k = 0; k < 32; ++k) {
        int r = rm[k];
        if (r != cur) {   // block-uniform branch
            float* dst = la + ((size_t)b * LL + cur) * DD + tid * 2;
            atomicAdd(dst, ax);
            atomicAdd(dst + 1, ay);
            ax = 0.f; ay = 0.f; cur = r;
        }
        const float2* p = (const float2*)(fr + (size_t)(t0 + k) * DD);
        float2 v = p[tid];
        ax += v.x; ay += v.y;
    }
    float* dst = la + ((size_t)b * LL + cur) * DD + tid * 2;
    atomicAdd(dst, ax);
    atomicAdd(dst + 1, ay);
}

// ---------------- Kernel 6: final fusion ----------------
__global__ __launch_bounds__(256) void k_final(const float* __restrict__ tok_logit,
                                               const float* __restrict__ fr_logit,
                                               const float* __restrict__ vid,
                                               const float* __restrict__ feat,
                                               const float* __restrict__ lse,
                                               const int* __restrict__ pse,
                                               const int* __restrict__ labels,
                                               const float* __restrict__ la,
                                               float* __restrict__ out) {
    int tid = threadIdx.x;
    __shared__ float red[4];
    __shared__ float s_tok, s_fr;
    __shared__ float nla[BB * LL];
    __shared__ float ntk[BB * CC];
    __shared__ float la_s[LL * DD];     // 32 KB
    __shared__ float sim_s[LL * CC];
    __shared__ float term_s[LL];
    __shared__ float batch_term[BB];

    // tok_loss (BCE with logits)
    float acc = 0.f;
    for (int i = tid; i < BB * CC; i += 256) {
        float x = tok_logit[i], y = vid[i];
        float lsp = fminf(x, 0.f) - log1pf(expf(-fabsf(x)));    // log_sigmoid(x)
        float lsn = fminf(-x, 0.f) - log1pf(expf(-fabsf(x)));   // log_sigmoid(-x)
        acc += -(y * lsp + (1.f - y) * lsn);
    }
    float w = wave_reduce_sum(acc);
    if ((tid & 63) == 0) red[tid >> 6] = w;
    __syncthreads();
    if (tid == 0) s_tok = (red[0] + red[1] + red[2] + red[3]) / (float)(BB * CC);
    __syncthreads();

    // fr_loss (mask all-ones)
    acc = 0.f;
    for (int i = tid; i < BB * TT; i += 256) {
        int p = pse[i];
        acc += lse[i] - fr_logit[(size_t)i * CC + p];
    }
    w = wave_reduce_sum(acc);
    if ((tid & 63) == 0) red[tid >> 6] = w;
    __syncthreads();
    if (tid == 0) s_fr = (red[0] + red[1] + red[2] + red[3]) / (float)(BB * TT);
    __syncthreads();

    // norms: 64 la rows + 192 tok rows = 256 rows, one per thread
    {
        const float* rowp;
        if (tid < BB * LL) rowp = la + (size_t)tid * DD;
        else {
            int k = tid - BB * LL;
            int b = k / CC, c = k - (k / CC) * CC;
            rowp = feat + ((size_t)b * (CC + TT) + c) * DD;
        }
        float ss = 0.f;
        for (int d = 0; d < DD; ++d) { float v = rowp[d]; ss += v * v; }
        float nn = fmaxf(sqrtf(ss), 1e-12f);
        if (tid < BB * LL) nla[tid] = nn; else ntk[tid - BB * LL] = nn;
    }
    __syncthreads();

    // glc per batch
    for (int b = 0; b < BB; ++b) {
        for (int i = tid; i < LL * DD; i += 256) la_s[i] = la[(size_t)b * LL * DD + i];
        __syncthreads();
        for (int e = tid; e < LL * CC; e += 256) {
            int l = e / CC, c = e - (e / CC) * CC;
            const float* tr = feat + ((size_t)b * (CC + TT) + c) * DD;
            const float* lr = la_s + l * DD;
            float dot = 0.f;
            for (int d = 0; d < DD; ++d) dot += lr[d] * tr[d];
            sim_s[e] = dot / (nla[b * LL + l] * ntk[b * CC + c]) * 10.0f;  // /TEMP
        }
        __syncthreads();
        if (tid < LL) {
            int l = tid;
            float mx = -INFINITY;
            for (int c = 0; c < CC; ++c) mx = fmaxf(mx, sim_s[l * CC + c]);
            float se = 0.f;
            for (int c = 0; c < CC; ++c) se += expf(sim_s[l * CC + c] - mx);
            int lab = labels[b * LL + l];
            term_s[l] = (mx + logf(se)) - sim_s[l * CC + lab];
        }
        __syncthreads();
        if (tid == 0) {
            float tsum = 0.f;
            for (int l = 0; l < LL; ++l) tsum += term_s[l];
            batch_term[b] = tsum / (float)LL;
        }
        __syncthreads();
    }
    if (tid == 0) {
        float glc = (batch_term[0] + batch_term[1] + batch_term[2] + batch_term[3]) / (float)BB;
        out[0] = s_tok + s_fr + 0.1f * glc;
    }
}

extern "C" void kernel_launch(void* const* d_in, const int* in_sizes, int n_in,
                              void* d_out, int out_size, void* d_ws, size_t ws_size,
                              hipStream_t stream) {
    (void)in_sizes; (void)n_in; (void)out_size; (void)ws_size;
    // input order: epoch, tok_logit, fr_logit, mask, transcript, vid_multi_hot, feat
    const float* tok_logit  = (const float*)d_in[1];
    const float* fr_logit   = (const float*)d_in[2];
    const int*   transcript = (const int*)d_in[4];
    const float* vid        = (const float*)d_in[5];
    const float* feat       = (const float*)d_in[6];
    // mask is all-ones (jnp.ones) -> folded into constants; epoch unused.

    char* ws = (char*)d_ws;
    // workspace layout (bytes); total ~3.41 MB
    float* prob   = (float*)(ws + 0);          // B*T*C
    float* logp   = (float*)(ws + 1572864);    // B*T*C
    float* lse    = (float*)(ws + 3145728);    // B*T
    float* score  = (float*)(ws + 3178496);    // B*T
    float* la     = (float*)(ws + 3211264);    // B*L*D
    int*   cand   = (int*)(ws + 3342336);      // B*64
    int*   labels = (int*)(ws + 3343360);      // B*L
    int*   pse    = (int*)(ws + 3343616);      // B*T
    int*   rowmap = (int*)(ws + 3376384);      // B*T
    float* out    = (float*)d_out;

    hipMemsetAsync(la, 0, (size_t)BB * LL * DD * sizeof(float), stream);

    k_softmax<<<BB * TT, 64, 0, stream>>>(fr_logit, prob, logp, lse);
    k_score<<<BB * TT, 64, 0, stream>>>(prob, logp, score);
    k_pick<<<BB, 256, 0, stream>>>(score, cand);
    k_dp<<<BB, 256, 0, stream>>>(prob, score, cand, transcript, labels, pse, rowmap);
    k_la<<<dim3(TT / 32, BB), 256, 0, stream>>>(feat, rowmap, la);
    k_final<<<1, 256, 0, stream>>>(tok_logit, fr_logit, vid, feat, lse, pse, labels, la, out);
}

// Round 3
// 236.915 us; speedup vs baseline: 2.6768x; 1.8188x over previous
//
#include <hip/hip_runtime.h>
#include <math.h>

// Problem constants (from reference)
#define BB 4
#define TT 2048
#define CC 48
#define DD 512
#define LL 16
#define NTR 15
#define NCAND 45
#define WINLEN 19   // int(T/L*0.15)
#define CSW 15
#define CCHALF 7

static __device__ __forceinline__ float wave_reduce_sum(float v) {
    for (int off = 32; off; off >>= 1) v += __shfl_down(v, off);
    return v;
}

// ---------------- Kernel 1: row softmax / log-softmax ----------------
__global__ __launch_bounds__(64) void k_softmax(const float* __restrict__ fr,
                                                float* __restrict__ prob,
                                                float* __restrict__ logp,
                                                float* __restrict__ lse) {
    int row = blockIdx.x;                 // b*T + t
    int c = threadIdx.x;
    const float* x = fr + (size_t)row * CC;
    float xv = (c < CC) ? x[c] : -INFINITY;
    float m = xv;
    for (int off = 32; off; off >>= 1) m = fmaxf(m, __shfl_down(m, off));
    m = __shfl(m, 0);
    float e = (c < CC) ? expf(xv - m) : 0.f;
    float s = wave_reduce_sum(e);
    s = __shfl(s, 0);
    if (c < CC) {
        float p = e / s;
        prob[(size_t)row * CC + c] = p;
        logp[(size_t)row * CC + c] = logf(p);
    }
    if (c == 0) lse[row] = m + logf(s);
}

// ---------------- Kernel 2: boundary (JS) score ----------------
// score[t] = -2/(81*ln2) * sum_{i<j} KER[i,j]*(kl[i,j]+kl[j,i])
__global__ __launch_bounds__(64) void k_score(const float* __restrict__ prob,
                                              const float* __restrict__ logp,
                                              float* __restrict__ score) {
    int row = blockIdx.x;
    int b = row / TT, t = row % TT;
    __shared__ float sp[9][CC];
    __shared__ float slp[9][CC];
    int tid = threadIdx.x;
    for (int idx = tid; idx < 9 * CC; idx += 64) {
        int i = idx / CC, c = idx - (idx / CC) * CC;
        int r = t - 4 + i;
        float pv = 0.f, lv = 0.f;
        if (r >= 0 && r < TT) {
            pv = prob[((size_t)b * TT + r) * CC + c];
            lv = logp[((size_t)b * TT + r) * CC + c];
        }
        sp[i][c] = pv;
        slp[i][c] = lv;
    }
    __syncthreads();
    float acc = 0.f;
    for (int item = tid; item < 36 * CC; item += 64) {
        int pidx = item / CC, c = item - pidx * CC;
        int i = 0, rem = pidx;
        while (rem >= 8 - i) { rem -= 8 - i; ++i; }
        int j = i + 1 + rem;
        float wgt = ((i < 4) == (j < 4)) ? 1.f : -1.f;
        float pi = sp[i][c], pj = sp[j][c];
        float logm = logf(0.5f * (pi + pj) + 1e-32f);
        float term = 0.f;
        if (pi > 0.f) term += pi * (slp[i][c] - logm);
        if (pj > 0.f) term += pj * (slp[j][c] - logm);
        acc += wgt * term;
    }
    acc = wave_reduce_sum(acc);
    if (tid == 0) {
        const float SC = -2.0f / (81.0f * 0.6931471805599453f);
        score[row] = (t == 0) ? -INFINITY : SC * acc;
    }
}

// ---------------- Kernel 3: greedy candidate pick + sort ----------------
__global__ __launch_bounds__(256) void k_pick(const float* __restrict__ score,
                                              int* __restrict__ cand) {
    int b = blockIdx.x;
    __shared__ float s[TT];
    __shared__ float rv[256];
    __shared__ int ri[256];
    __shared__ int cl[NCAND];
    int tid = threadIdx.x;
    for (int t = tid; t < TT; t += 256) s[t] = score[(size_t)b * TT + t];
    __syncthreads();
    for (int it = 0; it < NCAND; ++it) {
        float bv = -INFINITY;
        int bi = 0x7fffffff;
        for (int t = tid; t < TT; t += 256) {
            float v = s[t];
            if (v > bv) { bv = v; bi = t; }   // strict > keeps first index
        }
        rv[tid] = bv; ri[tid] = bi;
        __syncthreads();
        for (int off = 128; off; off >>= 1) {
            if (tid < off) {
                float v2 = rv[tid + off]; int i2 = ri[tid + off];
                if (v2 > rv[tid] || (v2 == rv[tid] && i2 < ri[tid])) { rv[tid] = v2; ri[tid] = i2; }
            }
            __syncthreads();
        }
        int imax = ri[0];
        if (tid == 0) cl[it] = imax;
        int lo = imax - WINLEN; if (lo < 0) lo = 0;
        int hi = imax + WINLEN; if (hi > TT - 1) hi = TT - 1;
        for (int t = lo + tid; t <= hi; t += 256) s[t] = -INFINITY;
        __syncthreads();
    }
    if (tid == 0) {
        for (int a = 1; a < NCAND; ++a) {
            int key = cl[a]; int b2 = a - 1;
            while (b2 >= 0 && cl[b2] > key) { cl[b2 + 1] = cl[b2]; --b2; }
            cl[b2 + 1] = key;
        }
        for (int a = 0; a < NCAND; ++a) cand[b * 64 + a] = cl[a];
    }
}

// ---------------- Kernel 4: cls + DP + backtrack + pse/rowmap + labels ----------------
__global__ __launch_bounds__(256) void k_dp(const float* __restrict__ prob,
                                            const float* __restrict__ score,
                                            const int* __restrict__ cand,
                                            const int* __restrict__ transcript,
                                            int* __restrict__ labels_out,
                                            int* __restrict__ pse,
                                            int* __restrict__ rowmap) {
    int b = blockIdx.x;
    __shared__ float cost[NTR][NCAND];
    __shared__ int tr_s[LL];
    __shared__ int cand_s[NCAND];
    __shared__ float backup_s[NCAND];
    __shared__ signed char dir_mat[NCAND][32];
    __shared__ int bdy_s[NTR];
    __shared__ int rank_s[LL];
    int tid = threadIdx.x;
    if (tid < LL) tr_s[tid] = transcript[b * LL + tid];
    if (tid < NCAND) {
        int cp = cand[b * 64 + tid];
        cand_s[tid] = cp;
        backup_s[tid] = score[(size_t)b * TT + cp];
    }
    __syncthreads();
    // cls matrix -> cost = -(conv/30 + backup)
    for (int e = tid; e < NTR * NCAND; e += 256) {
        int j = e / NCAND, ii = e - (e / NCAND) * NCAND;
        int cpos = cand_s[ii];
        int trj = tr_s[j], trj1 = tr_s[j + 1];
        float sum = 0.f;
        for (int k = 0; k < CSW; ++k) {
            int r = cpos - CCHALF + k;
            float a = 0.f, d2 = 0.f;
            if (r >= 0 && r < TT) {
                const float* pr = prob + ((size_t)b * TT + r) * CC;
                a = pr[trj]; d2 = pr[trj1];
            }
            sum += ((k < CCHALF) ? 1.f : -1.f) * (a - d2);
        }
        cost[j][ii] = -(sum / 30.f + backup_s[ii]);
    }
    __syncthreads();
    // DP on wave 0: state j = lane j (W = 31 states)
    if (tid < 64) {
        int lane = tid;
        float prev = INFINITY;
        if (lane == 0) prev = 0.f;              // ii=0 < 30
        if (lane == 1) prev = cost[0][0];
        if (lane < 31) dir_mat[0][lane] = (lane == 1) ? (signed char)1 : (signed char)0;
        for (int ii = 1; ii < NCAND; ++ii) {
            float dm1 = __shfl_up(prev, 1); if (lane < 1) dm1 = INFINITY;
            float dm2 = __shfl_up(prev, 2); if (lane < 2) dm2 = INFINITY;
            int trat = lane >> 1; if (trat > NTR - 1) trat = NTR - 1;
            float c_at = cost[trat][ii];
            float ev = fminf(prev, dm1);
            int ed = (prev < dm1) ? 0 : 1;
            float ov = c_at + fminf(dm1, dm2);
            int od = (dm1 < dm2) ? 1 : 2;
            float nv; int nd;
            if (lane >= 2) {
                if ((lane & 1) == 0) { nv = ev; nd = ed; }
                else { nv = ov; nd = od; }
            } else { nv = INFINITY; nd = 0; }
            if (lane == 0) { nv = (ii < NCAND - NTR) ? 0.f : INFINITY; nd = 0; }
            if (lane == 1) {
                nv = (ii <= NCAND - NTR) ? cost[0][ii] : INFINITY;
                nd = (ii <= NCAND - NTR) ? 1 : 0;
            }
            prev = nv;
            if (lane < 31) dir_mat[ii][lane] = (signed char)nd;
        }
        float v29 = __shfl(prev, 29);
        float v30 = __shfl(prev, 30);
        if (lane == 0) {
            int cur = (v30 < v29) ? 30 : 29;
            for (int ii = NCAND - 1; ii >= 0; --ii) {
                if (cur & 1) bdy_s[cur >> 1] = cand_s[ii];
                cur -= (int)dir_mat[ii][cur];
            }
            // sorted labels + rank of tr[j] among sorted labels
            int lab[LL];
            for (int i2 = 0; i2 < LL; ++i2) lab[i2] = tr_s[i2];
            for (int a2 = 1; a2 < LL; ++a2) {
                int key = lab[a2]; int b2 = a2 - 1;
                while (b2 >= 0 && lab[b2] > key) { lab[b2 + 1] = lab[b2]; --b2; }
                lab[b2 + 1] = key;
            }
            for (int i2 = 0; i2 < LL; ++i2) labels_out[b * LL + i2] = lab[i2];
            for (int j2 = 0; j2 < LL; ++j2) {
                int r2 = 0;
                for (int l2 = 0; l2 < LL; ++l2) if (lab[l2] == tr_s[j2]) r2 = l2;
                rank_s[j2] = r2;
            }
        }
    }
    __syncthreads();
    // pse[t] = tr[#boundaries <= t]; rowmap[t] = rank (la row) of that tr index
    for (int t = tid; t < TT; t += 256) {
        int cnt = 0;
        for (int j = 0; j < NTR; ++j) cnt += (t >= bdy_s[j]) ? 1 : 0;
        pse[b * TT + t] = tr_s[cnt];
        rowmap[b * TT + t] = rank_s[cnt];
    }
}

// ---------------- Kernel 5: segment feature sums (oh @ fr), tile-scatter ----------------
__global__ __launch_bounds__(256) void k_la(const float* __restrict__ feat,
                                            const int* __restrict__ rowmap,
                                            float* __restrict__ la) {
    int b = blockIdx.y;
    int t0 = blockIdx.x * 32;
    int tid = threadIdx.x;
    const float* fr = feat + ((size_t)b * (CC + TT) + CC) * DD;
    __shared__ int rm[32];
    if (tid < 32) rm[tid] = rowmap[b * TT + t0 + tid];
    __syncthreads();
    float ax = 0.f, ay = 0.f;
    int cur = rm[0];
    for (int k = 0; k < 32; ++k) {
        int r = rm[k];
        if (r != cur) {   // block-uniform branch
            float* dst = la + ((size_t)b * LL + cur) * DD + tid * 2;
            atomicAdd(dst, ax);
            atomicAdd(dst + 1, ay);
            ax = 0.f; ay = 0.f; cur = r;
        }
        const float2* p = (const float2*)(fr + (size_t)(t0 + k) * DD);
        float2 v = p[tid];
        ax += v.x; ay += v.y;
    }
    float* dst = la + ((size_t)b * LL + cur) * DD + tid * 2;
    atomicAdd(dst, ax);
    atomicAdd(dst + 1, ay);
}

// ---------------- Kernel 6a: row norms (one wave per row) ----------------
// waves 0..63: la rows; waves 64..255: tok feat rows
__global__ __launch_bounds__(256) void k_norms(const float* __restrict__ feat,
                                               const float* __restrict__ la,
                                               float* __restrict__ nla,
                                               float* __restrict__ ntk) {
    int wid = (blockIdx.x * 256 + threadIdx.x) >> 6;
    int lane = threadIdx.x & 63;
    const float* rowp;
    if (wid < BB * LL) rowp = la + (size_t)wid * DD;
    else {
        int k = wid - BB * LL;
        int b = k / CC, c = k - (k / CC) * CC;
        rowp = feat + ((size_t)b * (CC + TT) + c) * DD;
    }
    const float4* p = (const float4*)rowp;
    float ss = 0.f;
    for (int j = lane; j < DD / 4; j += 64) {
        float4 v = p[j];
        ss += v.x * v.x + v.y * v.y + v.z * v.z + v.w * v.w;
    }
    ss = wave_reduce_sum(ss);
    if (lane == 0) {
        float nn = fmaxf(sqrtf(ss), 1e-12f);
        if (wid < BB * LL) nla[wid] = nn; else ntk[wid - BB * LL] = nn;
    }
}

// ---------------- Kernel 6b: glc per-(b,l) row: 48 dots + logsumexp ----------------
__global__ __launch_bounds__(256) void k_glc(const float* __restrict__ feat,
                                             const float* __restrict__ la,
                                             const float* __restrict__ nla,
                                             const float* __restrict__ ntk,
                                             const int* __restrict__ labels,
                                             float* __restrict__ terms) {
    int l = blockIdx.x, b = blockIdx.y;
    __shared__ float la_s[DD];
    __shared__ float sim_s[CC];
    int tid = threadIdx.x;
    const float* lar = la + ((size_t)b * LL + l) * DD;
    ((float2*)la_s)[tid] = ((const float2*)lar)[tid];
    __syncthreads();
    int wave = tid >> 6, lane = tid & 63;
    float inv_nla = 10.0f / nla[b * LL + l];      // *1/TEMP folded
    for (int c = wave; c < CC; c += 4) {
        const float4* tr = (const float4*)(feat + ((size_t)b * (CC + TT) + c) * DD);
        const float4* ls = (const float4*)la_s;
        float dot = 0.f;
        for (int j = lane; j < DD / 4; j += 64) {
            float4 a = ls[j]; float4 v = tr[j];
            dot += a.x * v.x + a.y * v.y + a.z * v.z + a.w * v.w;
        }
        dot = wave_reduce_sum(dot);
        if (lane == 0) sim_s[c] = dot * inv_nla / ntk[b * CC + c];
    }
    __syncthreads();
    if (tid == 0) {
        float mx = -INFINITY;
        for (int c = 0; c < CC; ++c) mx = fmaxf(mx, sim_s[c]);
        float se = 0.f;
        for (int c = 0; c < CC; ++c) se += expf(sim_s[c] - mx);
        int lab = labels[b * LL + l];
        terms[b * LL + l] = (mx + logf(se)) - sim_s[lab];
    }
}

// ---------------- Kernel 6c: fr CE partial sum ----------------
__global__ __launch_bounds__(256) void k_fr(const float* __restrict__ fr_logit,
                                            const float* __restrict__ lse,
                                            const int* __restrict__ pse,
                                            float* __restrict__ fr_acc) {
    int i = blockIdx.x * 256 + threadIdx.x;     // 32 blocks cover B*T=8192
    int p = pse[i];
    float v = lse[i] - fr_logit[(size_t)i * CC + p];
    v = wave_reduce_sum(v);
    if ((threadIdx.x & 63) == 0) atomicAdd(fr_acc, v);
}

// ---------------- Kernel 6d: combine ----------------
__global__ __launch_bounds__(256) void k_combine(const float* __restrict__ tok_logit,
                                                 const float* __restrict__ vid,
                                                 const float* __restrict__ fr_acc,
                                                 const float* __restrict__ terms,
                                                 float* __restrict__ out) {
    int tid = threadIdx.x;
    __shared__ float red[4];
    float acc = 0.f;
    if (tid < BB * CC) {
        float x = tok_logit[tid], y = vid[tid];
        float lsp = fminf(x, 0.f) - log1pf(expf(-fabsf(x)));
        float lsn = fminf(-x, 0.f) - log1pf(expf(-fabsf(x)));
        acc = -(y * lsp + (1.f - y) * lsn);
    }
    float w = wave_reduce_sum(acc);
    if ((tid & 63) == 0) red[tid >> 6] = w;
    __syncthreads();
    if (tid == 0) {
        float s_tok = (red[0] + red[1] + red[2] + red[3]) / (float)(BB * CC);
        float s_fr = fr_acc[0] / (float)(BB * TT);
        float g = 0.f;
        for (int i = 0; i < BB * LL; ++i) g += terms[i];
        float glc = g / (float)(BB * LL);
        out[0] = s_tok + s_fr + 0.1f * glc;
    }
}

extern "C" void kernel_launch(void* const* d_in, const int* in_sizes, int n_in,
                              void* d_out, int out_size, void* d_ws, size_t ws_size,
                              hipStream_t stream) {
    (void)in_sizes; (void)n_in; (void)out_size; (void)ws_size;
    // input order: epoch, tok_logit, fr_logit, mask, transcript, vid_multi_hot, feat
    const float* tok_logit  = (const float*)d_in[1];
    const float* fr_logit   = (const float*)d_in[2];
    const int*   transcript = (const int*)d_in[4];
    const float* vid        = (const float*)d_in[5];
    const float* feat       = (const float*)d_in[6];

    char* ws = (char*)d_ws;
    float* prob   = (float*)(ws + 0);          // B*T*C
    float* logp   = (float*)(ws + 1572864);    // B*T*C
    float* lse    = (float*)(ws + 3145728);    // B*T
    float* score  = (float*)(ws + 3178496);    // B*T
    float* la     = (float*)(ws + 3211264);    // B*L*D (131072 B)
    float* fr_acc = (float*)(ws + 3342336);    // 1 (zeroed with la)
    float* terms  = (float*)(ws + 3342592);    // B*L
    float* nla    = (float*)(ws + 3342848);    // B*L
    float* ntk    = (float*)(ws + 3343104);    // B*C
    int*   cand   = (int*)(ws + 3343872);      // B*64
    int*   labels = (int*)(ws + 3344896);      // B*L
    int*   pse    = (int*)(ws + 3345152);      // B*T
    int*   rowmap = (int*)(ws + 3377920);      // B*T
    float* out    = (float*)d_out;

    // zero la + fr_acc in one memset (contiguous region)
    hipMemsetAsync(la, 0, 131072 + 256, stream);

    k_softmax<<<BB * TT, 64, 0, stream>>>(fr_logit, prob, logp, lse);
    k_score<<<BB * TT, 64, 0, stream>>>(prob, logp, score);
    k_pick<<<BB, 256, 0, stream>>>(score, cand);
    k_dp<<<BB, 256, 0, stream>>>(prob, score, cand, transcript, labels, pse, rowmap);
    k_la<<<dim3(TT / 32, BB), 256, 0, stream>>>(feat, rowmap, la);
    k_norms<<<64, 256, 0, stream>>>(feat, la, nla, ntk);
    k_glc<<<dim3(LL, BB), 256, 0, stream>>>(feat, la, nla, ntk, labels, terms);
    k_fr<<<BB * TT / 256, 256, 0, stream>>>(fr_logit, lse, pse, fr_acc);
    k_combine<<<1, 256, 0, stream>>>(tok_logit, vid, fr_acc, terms, out);
}

// Round 4
// 213.237 us; speedup vs baseline: 2.9740x; 1.1110x over previous
//
#include <hip/hip_runtime.h>
#include <math.h>

// Problem constants (from reference)
#define BB 4
#define TT 2048
#define CC 48
#define DD 512
#define LL 16
#define NTR 15
#define NCAND 45
#define WINLEN 19   // int(T/L*0.15)
#define CSW 15
#define CCHALF 7

static __device__ __forceinline__ float wave_reduce_sum(float v) {
    for (int off = 32; off; off >>= 1) v += __shfl_down(v, off);
    return v;
}

// ---------------- Kernel 1: row softmax / log-softmax ----------------
__global__ __launch_bounds__(64) void k_softmax(const float* __restrict__ fr,
                                                float* __restrict__ prob,
                                                float* __restrict__ logp,
                                                float* __restrict__ lse) {
    int row = blockIdx.x;                 // b*T + t
    int c = threadIdx.x;
    const float* x = fr + (size_t)row * CC;
    float xv = (c < CC) ? x[c] : -INFINITY;
    float m = xv;
    for (int off = 32; off; off >>= 1) m = fmaxf(m, __shfl_down(m, off));
    m = __shfl(m, 0);
    float e = (c < CC) ? expf(xv - m) : 0.f;
    float s = wave_reduce_sum(e);
    s = __shfl(s, 0);
    if (c < CC) {
        float p = e / s;
        prob[(size_t)row * CC + c] = p;
        logp[(size_t)row * CC + c] = logf(p);
    }
    if (c == 0) lse[row] = m + logf(s);
}

// ---------------- Kernel 2: boundary (JS) score ----------------
// score[t] = -2/(81*ln2) * sum_{i<j} KER[i,j]*(kl[i,j]+kl[j,i])
__global__ __launch_bounds__(64) void k_score(const float* __restrict__ prob,
                                              const float* __restrict__ logp,
                                              float* __restrict__ score) {
    int row = blockIdx.x;
    int b = row / TT, t = row % TT;
    __shared__ float sp[9][CC];
    __shared__ float slp[9][CC];
    int tid = threadIdx.x;
    for (int idx = tid; idx < 9 * CC; idx += 64) {
        int i = idx / CC, c = idx - (idx / CC) * CC;
        int r = t - 4 + i;
        float pv = 0.f, lv = 0.f;
        if (r >= 0 && r < TT) {
            pv = prob[((size_t)b * TT + r) * CC + c];
            lv = logp[((size_t)b * TT + r) * CC + c];
        }
        sp[i][c] = pv;
        slp[i][c] = lv;
    }
    __syncthreads();
    float acc = 0.f;
    for (int item = tid; item < 36 * CC; item += 64) {
        int pidx = item / CC, c = item - pidx * CC;
        int i = 0, rem = pidx;
        while (rem >= 8 - i) { rem -= 8 - i; ++i; }
        int j = i + 1 + rem;
        float wgt = ((i < 4) == (j < 4)) ? 1.f : -1.f;
        float pi = sp[i][c], pj = sp[j][c];
        float logm = logf(0.5f * (pi + pj) + 1e-32f);
        float term = 0.f;
        if (pi > 0.f) term += pi * (slp[i][c] - logm);
        if (pj > 0.f) term += pj * (slp[j][c] - logm);
        acc += wgt * term;
    }
    acc = wave_reduce_sum(acc);
    if (tid == 0) {
        const float SC = -2.0f / (81.0f * 0.6931471805599453f);
        score[row] = (t == 0) ? -INFINITY : SC * acc;
    }
}

// ---------------- Kernel 3: greedy pick, single-wave incremental argmax ----------------
// Lane j owns chunk [32j, 32j+32). LDS padded: element t lives at s[t + t/32]
// -> per-lane chunk scans are bank-conflict-free; coalesced fill is 2-way (free).
__global__ __launch_bounds__(64) void k_pick(const float* __restrict__ score,
                                             int* __restrict__ cand) {
    int b = blockIdx.x;
    int lane = threadIdx.x;
    __shared__ float s[64 * 33];
    __shared__ int cl[NCAND];
    for (int t = lane; t < TT; t += 64) s[t + (t >> 5)] = score[(size_t)b * TT + t];
    __syncthreads();
    // per-lane chunk max with first-index tie-break
    float bv = -INFINITY; int bp = lane * 32;
    for (int k = 0; k < 32; ++k) {
        float v = s[lane * 33 + k];
        if (v > bv) { bv = v; bp = lane * 32 + k; }
    }
    for (int it = 0; it < NCAND; ++it) {
        // butterfly argmax over 64 chunk maxima (no barriers)
        float mv = bv; int mp = bp;
        for (int off = 1; off < 64; off <<= 1) {
            float ov = __shfl_xor(mv, off);
            int op = __shfl_xor(mp, off);
            if (ov > mv || (ov == mv && op < mp)) { mv = ov; mp = op; }
        }
        if (lane == 0) cl[it] = mp;
        int lo = mp - WINLEN; if (lo < 0) lo = 0;
        int hi = mp + WINLEN; if (hi > TT - 1) hi = TT - 1;
        int t = lo + lane;
        if (t <= hi) s[t + (t >> 5)] = -INFINITY;
        __syncthreads();    // single-wave: just a waitcnt, cheap
        int jlo = lo >> 5, jhi = hi >> 5;
        if (lane >= jlo && lane <= jhi) {    // <=3 dirty chunks rescan
            float nv = -INFINITY; int np = lane * 32;
            for (int k = 0; k < 32; ++k) {
                float v = s[lane * 33 + k];
                if (v > nv) { nv = v; np = lane * 32 + k; }
            }
            bv = nv; bp = np;
        }
    }
    __syncthreads();
    // rank-based parallel sort (positions are distinct)
    if (lane < NCAND) {
        int my = cl[lane];
        int rank = 0;
        for (int i = 0; i < NCAND; ++i) rank += (cl[i] < my) ? 1 : 0;
        cand[b * 64 + rank] = my;
    }
}

// ---------------- Kernel 4: cls + DP + backtrack + pse/rowmap + labels ----------------
__global__ __launch_bounds__(256) void k_dp(const float* __restrict__ prob,
                                            const float* __restrict__ score,
                                            const int* __restrict__ cand,
                                            const int* __restrict__ transcript,
                                            int* __restrict__ labels_out,
                                            int* __restrict__ pse,
                                            int* __restrict__ rowmap) {
    int b = blockIdx.x;
    __shared__ float cost[NTR][NCAND];
    __shared__ int tr_s[LL];
    __shared__ int cand_s[NCAND];
    __shared__ float backup_s[NCAND];
    __shared__ signed char dir_mat[NCAND][32];
    __shared__ int bdy_s[NTR];
    __shared__ int rank_s[LL];
    int tid = threadIdx.x;
    if (tid < LL) tr_s[tid] = transcript[b * LL + tid];
    if (tid < NCAND) {
        int cp = cand[b * 64 + tid];
        cand_s[tid] = cp;
        backup_s[tid] = score[(size_t)b * TT + cp];
    }
    __syncthreads();
    // cls matrix -> cost = -(conv/30 + backup)
    for (int e = tid; e < NTR * NCAND; e += 256) {
        int j = e / NCAND, ii = e - (e / NCAND) * NCAND;
        int cpos = cand_s[ii];
        int trj = tr_s[j], trj1 = tr_s[j + 1];
        float sum = 0.f;
        for (int k = 0; k < CSW; ++k) {
            int r = cpos - CCHALF + k;
            float a = 0.f, d2 = 0.f;
            if (r >= 0 && r < TT) {
                const float* pr = prob + ((size_t)b * TT + r) * CC;
                a = pr[trj]; d2 = pr[trj1];
            }
            sum += ((k < CCHALF) ? 1.f : -1.f) * (a - d2);
        }
        cost[j][ii] = -(sum / 30.f + backup_s[ii]);
    }
    __syncthreads();
    // DP on wave 0: state j = lane j (W = 31 states)
    if (tid < 64) {
        int lane = tid;
        float prev = INFINITY;
        if (lane == 0) prev = 0.f;              // ii=0 < 30
        if (lane == 1) prev = cost[0][0];
        if (lane < 31) dir_mat[0][lane] = (lane == 1) ? (signed char)1 : (signed char)0;
        for (int ii = 1; ii < NCAND; ++ii) {
            float dm1 = __shfl_up(prev, 1); if (lane < 1) dm1 = INFINITY;
            float dm2 = __shfl_up(prev, 2); if (lane < 2) dm2 = INFINITY;
            int trat = lane >> 1; if (trat > NTR - 1) trat = NTR - 1;
            float c_at = cost[trat][ii];
            float ev = fminf(prev, dm1);
            int ed = (prev < dm1) ? 0 : 1;
            float ov = c_at + fminf(dm1, dm2);
            int od = (dm1 < dm2) ? 1 : 2;
            float nv; int nd;
            if (lane >= 2) {
                if ((lane & 1) == 0) { nv = ev; nd = ed; }
                else { nv = ov; nd = od; }
            } else { nv = INFINITY; nd = 0; }
            if (lane == 0) { nv = (ii < NCAND - NTR) ? 0.f : INFINITY; nd = 0; }
            if (lane == 1) {
                nv = (ii <= NCAND - NTR) ? cost[0][ii] : INFINITY;
                nd = (ii <= NCAND - NTR) ? 1 : 0;
            }
            prev = nv;
            if (lane < 31) dir_mat[ii][lane] = (signed char)nd;
        }
        float v29 = __shfl(prev, 29);
        float v30 = __shfl(prev, 30);
        if (lane == 0) {
            int cur = (v30 < v29) ? 30 : 29;
            for (int ii = NCAND - 1; ii >= 0; --ii) {
                if (cur & 1) bdy_s[cur >> 1] = cand_s[ii];
                cur -= (int)dir_mat[ii][cur];
            }
            // sorted labels + rank of tr[j] among sorted labels
            int lab[LL];
            for (int i2 = 0; i2 < LL; ++i2) lab[i2] = tr_s[i2];
            for (int a2 = 1; a2 < LL; ++a2) {
                int key = lab[a2]; int b2 = a2 - 1;
                while (b2 >= 0 && lab[b2] > key) { lab[b2 + 1] = lab[b2]; --b2; }
                lab[b2 + 1] = key;
            }
            for (int i2 = 0; i2 < LL; ++i2) labels_out[b * LL + i2] = lab[i2];
            for (int j2 = 0; j2 < LL; ++j2) {
                int r2 = 0;
                for (int l2 = 0; l2 < LL; ++l2) if (lab[l2] == tr_s[j2]) r2 = l2;
                rank_s[j2] = r2;
            }
        }
    }
    __syncthreads();
    // pse[t] = tr[#boundaries <= t]; rowmap[t] = rank (la row) of that tr index
    for (int t = tid; t < TT; t += 256) {
        int cnt = 0;
        for (int j = 0; j < NTR; ++j) cnt += (t >= bdy_s[j]) ? 1 : 0;
        pse[b * TT + t] = tr_s[cnt];
        rowmap[b * TT + t] = rank_s[cnt];
    }
}

// ---------------- Kernel 5: segment feature sums (oh @ fr), tile-scatter ----------------
__global__ __launch_bounds__(256) void k_la(const float* __restrict__ feat,
                                            const int* __restrict__ rowmap,
                                            float* __restrict__ la) {
    int b = blockIdx.y;
    int t0 = blockIdx.x * 32;
    int tid = threadIdx.x;
    const float* fr = feat + ((size_t)b * (CC + TT) + CC) * DD;
    __shared__ int rm[32];
    if (tid < 32) rm[tid] = rowmap[b * TT + t0 + tid];
    __syncthreads();
    float ax = 0.f, ay = 0.f;
    int cur = rm[0];
    for (int k = 0; k < 32; ++k) {
        int r = rm[k];
        if (r != cur) {   // block-uniform branch
            float* dst = la + ((size_t)b * LL + cur) * DD + tid * 2;
            atomicAdd(dst, ax);
            atomicAdd(dst + 1, ay);
            ax = 0.f; ay = 0.f; cur = r;
        }
        const float2* p = (const float2*)(fr + (size_t)(t0 + k) * DD);
        float2 v = p[tid];
        ax += v.x; ay += v.y;
    }
    float* dst = la + ((size_t)b * LL + cur) * DD + tid * 2;
    atomicAdd(dst, ax);
    atomicAdd(dst + 1, ay);
}

// ---------------- Kernel 6a: row norms (one wave per row) ----------------
// waves 0..63: la rows; waves 64..255: tok feat rows
__global__ __launch_bounds__(256) void k_norms(const float* __restrict__ feat,
                                               const float* __restrict__ la,
                                               float* __restrict__ nla,
                                               float* __restrict__ ntk) {
    int wid = (blockIdx.x * 256 + threadIdx.x) >> 6;
    int lane = threadIdx.x & 63;
    const float* rowp;
    if (wid < BB * LL) rowp = la + (size_t)wid * DD;
    else {
        int k = wid - BB * LL;
        int b = k / CC, c = k - (k / CC) * CC;
        rowp = feat + ((size_t)b * (CC + TT) + c) * DD;
    }
    const float4* p = (const float4*)rowp;
    float ss = 0.f;
    for (int j = lane; j < DD / 4; j += 64) {
        float4 v = p[j];
        ss += v.x * v.x + v.y * v.y + v.z * v.z + v.w * v.w;
    }
    ss = wave_reduce_sum(ss);
    if (lane == 0) {
        float nn = fmaxf(sqrtf(ss), 1e-12f);
        if (wid < BB * LL) nla[wid] = nn; else ntk[wid - BB * LL] = nn;
    }
}

// ---------------- Kernel 6b: glc per-(b,l) row: 48 dots + logsumexp ----------------
__global__ __launch_bounds__(256) void k_glc(const float* __restrict__ feat,
                                             const float* __restrict__ la,
                                             const float* __restrict__ nla,
                                             const float* __restrict__ ntk,
                                             const int* __restrict__ labels,
                                             float* __restrict__ terms) {
    int l = blockIdx.x, b = blockIdx.y;
    __shared__ float la_s[DD];
    __shared__ float sim_s[CC];
    int tid = threadIdx.x;
    const float* lar = la + ((size_t)b * LL + l) * DD;
    ((float2*)la_s)[tid] = ((const float2*)lar)[tid];
    __syncthreads();
    int wave = tid >> 6, lane = tid & 63;
    float inv_nla = 10.0f / nla[b * LL + l];      // *1/TEMP folded
    for (int c = wave; c < CC; c += 4) {
        const float4* tr = (const float4*)(feat + ((size_t)b * (CC + TT) + c) * DD);
        const float4* ls = (const float4*)la_s;
        float dot = 0.f;
        for (int j = lane; j < DD / 4; j += 64) {
            float4 a = ls[j]; float4 v = tr[j];
            dot += a.x * v.x + a.y * v.y + a.z * v.z + a.w * v.w;
        }
        dot = wave_reduce_sum(dot);
        if (lane == 0) sim_s[c] = dot * inv_nla / ntk[b * CC + c];
    }
    __syncthreads();
    if (tid == 0) {
        float mx = -INFINITY;
        for (int c = 0; c < CC; ++c) mx = fmaxf(mx, sim_s[c]);
        float se = 0.f;
        for (int c = 0; c < CC; ++c) se += expf(sim_s[c] - mx);
        int lab = labels[b * LL + l];
        terms[b * LL + l] = (mx + logf(se)) - sim_s[lab];
    }
}

// ---------------- Kernel 6c: fr CE partial sum ----------------
__global__ __launch_bounds__(256) void k_fr(const float* __restrict__ fr_logit,
                                            const float* __restrict__ lse,
                                            const int* __restrict__ pse,
                                            float* __restrict__ fr_acc) {
    int i = blockIdx.x * 256 + threadIdx.x;     // 32 blocks cover B*T=8192
    int p = pse[i];
    float v = lse[i] - fr_logit[(size_t)i * CC + p];
    v = wave_reduce_sum(v);
    if ((threadIdx.x & 63) == 0) atomicAdd(fr_acc, v);
}

// ---------------- Kernel 6d: combine ----------------
__global__ __launch_bounds__(256) void k_combine(const float* __restrict__ tok_logit,
                                                 const float* __restrict__ vid,
                                                 const float* __restrict__ fr_acc,
                                                 const float* __restrict__ terms,
                                                 float* __restrict__ out) {
    int tid = threadIdx.x;
    __shared__ float red[4];
    float acc = 0.f;
    if (tid < BB * CC) {
        float x = tok_logit[tid], y = vid[tid];
        float lsp = fminf(x, 0.f) - log1pf(expf(-fabsf(x)));
        float lsn = fminf(-x, 0.f) - log1pf(expf(-fabsf(x)));
        acc = -(y * lsp + (1.f - y) * lsn);
    }
    float w = wave_reduce_sum(acc);
    if ((tid & 63) == 0) red[tid >> 6] = w;
    __syncthreads();
    if (tid == 0) {
        float s_tok = (red[0] + red[1] + red[2] + red[3]) / (float)(BB * CC);
        float s_fr = fr_acc[0] / (float)(BB * TT);
        float g = 0.f;
        for (int i = 0; i < BB * LL; ++i) g += terms[i];
        float glc = g / (float)(BB * LL);
        out[0] = s_tok + s_fr + 0.1f * glc;
    }
}

extern "C" void kernel_launch(void* const* d_in, const int* in_sizes, int n_in,
                              void* d_out, int out_size, void* d_ws, size_t ws_size,
                              hipStream_t stream) {
    (void)in_sizes; (void)n_in; (void)out_size; (void)ws_size;
    // input order: epoch, tok_logit, fr_logit, mask, transcript, vid_multi_hot, feat
    const float* tok_logit  = (const float*)d_in[1];
    const float* fr_logit   = (const float*)d_in[2];
    const int*   transcript = (const int*)d_in[4];
    const float* vid        = (const float*)d_in[5];
    const float* feat       = (const float*)d_in[6];

    char* ws = (char*)d_ws;
    float* prob   = (float*)(ws + 0);          // B*T*C
    float* logp   = (float*)(ws + 1572864);    // B*T*C
    float* lse    = (float*)(ws + 3145728);    // B*T
    float* score  = (float*)(ws + 3178496);    // B*T
    float* la     = (float*)(ws + 3211264);    // B*L*D (131072 B)
    float* fr_acc = (float*)(ws + 3342336);    // 1 (zeroed with la)
    float* terms  = (float*)(ws + 3342592);    // B*L
    float* nla    = (float*)(ws + 3342848);    // B*L
    float* ntk    = (float*)(ws + 3343104);    // B*C
    int*   cand   = (int*)(ws + 3343872);      // B*64
    int*   labels = (int*)(ws + 3344896);      // B*L
    int*   pse    = (int*)(ws + 3345152);      // B*T
    int*   rowmap = (int*)(ws + 3377920);      // B*T
    float* out    = (float*)d_out;

    // zero la + fr_acc in one memset (contiguous region)
    hipMemsetAsync(la, 0, 131072 + 256, stream);

    k_softmax<<<BB * TT, 64, 0, stream>>>(fr_logit, prob, logp, lse);
    k_score<<<BB * TT, 64, 0, stream>>>(prob, logp, score);
    k_pick<<<BB, 64, 0, stream>>>(score, cand);
    k_dp<<<BB, 256, 0, stream>>>(prob, score, cand, transcript, labels, pse, rowmap);
    k_la<<<dim3(TT / 32, BB), 256, 0, stream>>>(feat, rowmap, la);
    k_norms<<<64, 256, 0, stream>>>(feat, la, nla, ntk);
    k_glc<<<dim3(LL, BB), 256, 0, stream>>>(feat, la, nla, ntk, labels, terms);
    k_fr<<<BB * TT / 256, 256, 0, stream>>>(fr_logit, lse, pse, fr_acc);
    k_combine<<<1, 256, 0, stream>>>(tok_logit, vid, fr_acc, terms, out);
}

// Round 5
// 193.488 us; speedup vs baseline: 3.2776x; 1.1021x over previous
//
#include <hip/hip_runtime.h>
#include <math.h>

// Problem constants (from reference)
#define BB 4
#define TT 2048
#define CC 48
#define DD 512
#define LL 16
#define NTR 15
#define NCAND 45
#define WINLEN 19   // int(T/L*0.15)
#define CSW 15
#define CCHALF 7

static __device__ __forceinline__ float wave_reduce_sum(float v) {
    for (int off = 32; off; off >>= 1) v += __shfl_down(v, off);
    return v;
}

// DPP max step: result lanes per ctrl get src lane's value, invalid lanes keep old(=x)
#define DPPMAX(x, ctrl) fmaxf((x), __int_as_float(__builtin_amdgcn_update_dpp( \
    __float_as_int(x), __float_as_int(x), (ctrl), 0xF, 0xF, false)))

// ---------------- Kernel 1: row softmax / log-softmax ----------------
__global__ __launch_bounds__(64) void k_softmax(const float* __restrict__ fr,
                                                float* __restrict__ prob,
                                                float* __restrict__ logp,
                                                float* __restrict__ lse) {
    int row = blockIdx.x;                 // b*T + t
    int c = threadIdx.x;
    const float* x = fr + (size_t)row * CC;
    float xv = (c < CC) ? x[c] : -INFINITY;
    float m = xv;
    for (int off = 32; off; off >>= 1) m = fmaxf(m, __shfl_down(m, off));
    m = __shfl(m, 0);
    float e = (c < CC) ? expf(xv - m) : 0.f;
    float s = wave_reduce_sum(e);
    s = __shfl(s, 0);
    if (c < CC) {
        float p = e / s;
        prob[(size_t)row * CC + c] = p;
        logp[(size_t)row * CC + c] = logf(p);
    }
    if (c == 0) lse[row] = m + logf(s);
}

// ---------------- Kernel 2: boundary (JS) score ----------------
// score[t] = -2/(81*ln2) * sum_{i<j} KER[i,j]*(kl[i,j]+kl[j,i])
__global__ __launch_bounds__(64) void k_score(const float* __restrict__ prob,
                                              const float* __restrict__ logp,
                                              float* __restrict__ score) {
    int row = blockIdx.x;
    int b = row / TT, t = row % TT;
    __shared__ float sp[9][CC];
    __shared__ float slp[9][CC];
    int tid = threadIdx.x;
    for (int idx = tid; idx < 9 * CC; idx += 64) {
        int i = idx / CC, c = idx - (idx / CC) * CC;
        int r = t - 4 + i;
        float pv = 0.f, lv = 0.f;
        if (r >= 0 && r < TT) {
            pv = prob[((size_t)b * TT + r) * CC + c];
            lv = logp[((size_t)b * TT + r) * CC + c];
        }
        sp[i][c] = pv;
        slp[i][c] = lv;
    }
    __syncthreads();
    float acc = 0.f;
    for (int item = tid; item < 36 * CC; item += 64) {
        int pidx = item / CC, c = item - pidx * CC;
        int i = 0, rem = pidx;
        while (rem >= 8 - i) { rem -= 8 - i; ++i; }
        int j = i + 1 + rem;
        float wgt = ((i < 4) == (j < 4)) ? 1.f : -1.f;
        float pi = sp[i][c], pj = sp[j][c];
        float logm = logf(0.5f * (pi + pj) + 1e-32f);
        float term = 0.f;
        if (pi > 0.f) term += pi * (slp[i][c] - logm);
        if (pj > 0.f) term += pj * (slp[j][c] - logm);
        acc += wgt * term;
    }
    acc = wave_reduce_sum(acc);
    if (tid == 0) {
        const float SC = -2.0f / (81.0f * 0.6931471805599453f);
        score[row] = (t == 0) ? -INFINITY : SC * acc;
    }
}

// ---------------- Kernel 3: greedy pick, register-resident + DPP reduce ----------------
// Lane j owns chunk [32j, 32j+32) in a VGPR array. Per iteration:
//   in-lane argmax (descending compare chain, first-index exact) ->
//   DPP cross-lane max -> ballot/ffs for lowest lane -> readlane position ->
//   register-mask suppression. No LDS in the hot loop.
__global__ __launch_bounds__(64) void k_pick(const float* __restrict__ score,
                                             int* __restrict__ cand) {
    int b = blockIdx.x;
    int lane = threadIdx.x;
    __shared__ float s[64 * 33];
    __shared__ int cl[NCAND];
    for (int t = lane; t < TT; t += 64) s[t + (t >> 5)] = score[(size_t)b * TT + t];
    __syncthreads();
    float v[32];
    #pragma unroll
    for (int k = 0; k < 32; ++k) v[k] = s[lane * 33 + k];   // stride-33: conflict-free
    int base = lane << 5;
    for (int it = 0; it < NCAND; ++it) {
        // in-lane argmax, first index wins ties (descending k, >=)
        float best = -INFINITY; int bi = 0;
        #pragma unroll
        for (int k = 31; k >= 0; --k) {
            if (v[k] >= best) { best = v[k]; bi = k; }
        }
        // cross-lane max via DPP (VALU latency, no LDS)
        float m = best;
        m = DPPMAX(m, 0x111);   // row_shr:1
        m = DPPMAX(m, 0x112);   // row_shr:2
        m = DPPMAX(m, 0x114);   // row_shr:4
        m = DPPMAX(m, 0x118);   // row_shr:8  -> lane 15 of each row has row max
        m = DPPMAX(m, 0x142);   // row_bcast:15 -> lane 31/63 have half maxes
        m = DPPMAX(m, 0x143);   // row_bcast:31 -> lane 63 has global max
        float gmax = __int_as_float(__builtin_amdgcn_readlane(__float_as_int(m), 63));
        // lowest lane holding gmax = earliest chunk = first global index
        unsigned long long ball = __ballot(best == gmax);
        int sl = (int)(__ffsll(ball) - 1);
        int mp = __builtin_amdgcn_readlane(base + bi, sl);
        if (lane == 0) cl[it] = mp;
        // suppress [mp-WINLEN, mp+WINLEN] within this lane's chunk (register mask)
        int llo = mp - WINLEN - base;
        int lhi = mp + WINLEN - base;
        unsigned lowm = (llo <= 0) ? 0xffffffffu : ((llo >= 32) ? 0u : ~((1u << llo) - 1u));
        unsigned him  = (lhi >= 31) ? 0xffffffffu : ((lhi < 0) ? 0u : ((2u << lhi) - 1u));
        unsigned wm = lowm & him;
        #pragma unroll
        for (int k = 0; k < 32; ++k)
            if (wm & (1u << k)) v[k] = -INFINITY;
    }
    __syncthreads();
    // rank-based parallel sort (positions are distinct)
    if (lane < NCAND) {
        int my = cl[lane];
        int rank = 0;
        for (int i = 0; i < NCAND; ++i) rank += (cl[i] < my) ? 1 : 0;
        cand[b * 64 + rank] = my;
    }
}

// ---------------- Kernel 4: cls + DP + backtrack + pse/rowmap + labels ----------------
__global__ __launch_bounds__(256) void k_dp(const float* __restrict__ prob,
                                            const float* __restrict__ score,
                                            const int* __restrict__ cand,
                                            const int* __restrict__ transcript,
                                            int* __restrict__ labels_out,
                                            int* __restrict__ pse,
                                            int* __restrict__ rowmap) {
    int b = blockIdx.x;
    __shared__ float cost[NTR][NCAND];
    __shared__ int tr_s[LL];
    __shared__ int cand_s[NCAND];
    __shared__ float backup_s[NCAND];
    __shared__ signed char dir_mat[NCAND][32];
    __shared__ int bdy_s[NTR];
    __shared__ int rank_s[LL];
    int tid = threadIdx.x;
    if (tid < LL) tr_s[tid] = transcript[b * LL + tid];
    if (tid < NCAND) {
        int cp = cand[b * 64 + tid];
        cand_s[tid] = cp;
        backup_s[tid] = score[(size_t)b * TT + cp];
    }
    __syncthreads();
    // cls matrix -> cost = -(conv/30 + backup)
    for (int e = tid; e < NTR * NCAND; e += 256) {
        int j = e / NCAND, ii = e - (e / NCAND) * NCAND;
        int cpos = cand_s[ii];
        int trj = tr_s[j], trj1 = tr_s[j + 1];
        float sum = 0.f;
        for (int k = 0; k < CSW; ++k) {
            int r = cpos - CCHALF + k;
            float a = 0.f, d2 = 0.f;
            if (r >= 0 && r < TT) {
                const float* pr = prob + ((size_t)b * TT + r) * CC;
                a = pr[trj]; d2 = pr[trj1];
            }
            sum += ((k < CCHALF) ? 1.f : -1.f) * (a - d2);
        }
        cost[j][ii] = -(sum / 30.f + backup_s[ii]);
    }
    __syncthreads();
    // DP on wave 0: state j = lane j (W = 31 states)
    if (tid < 64) {
        int lane = tid;
        float prev = INFINITY;
        if (lane == 0) prev = 0.f;              // ii=0 < 30
        if (lane == 1) prev = cost[0][0];
        if (lane < 31) dir_mat[0][lane] = (lane == 1) ? (signed char)1 : (signed char)0;
        for (int ii = 1; ii < NCAND; ++ii) {
            float dm1 = __shfl_up(prev, 1); if (lane < 1) dm1 = INFINITY;
            float dm2 = __shfl_up(prev, 2); if (lane < 2) dm2 = INFINITY;
            int trat = lane >> 1; if (trat > NTR - 1) trat = NTR - 1;
            float c_at = cost[trat][ii];
            float ev = fminf(prev, dm1);
            int ed = (prev < dm1) ? 0 : 1;
            float ov = c_at + fminf(dm1, dm2);
            int od = (dm1 < dm2) ? 1 : 2;
            float nv; int nd;
            if (lane >= 2) {
                if ((lane & 1) == 0) { nv = ev; nd = ed; }
                else { nv = ov; nd = od; }
            } else { nv = INFINITY; nd = 0; }
            if (lane == 0) { nv = (ii < NCAND - NTR) ? 0.f : INFINITY; nd = 0; }
            if (lane == 1) {
                nv = (ii <= NCAND - NTR) ? cost[0][ii] : INFINITY;
                nd = (ii <= NCAND - NTR) ? 1 : 0;
            }
            prev = nv;
            if (lane < 31) dir_mat[ii][lane] = (signed char)nd;
        }
        float v29 = __shfl(prev, 29);
        float v30 = __shfl(prev, 30);
        if (lane == 0) {
            int cur = (v30 < v29) ? 30 : 29;
            for (int ii = NCAND - 1; ii >= 0; --ii) {
                if (cur & 1) bdy_s[cur >> 1] = cand_s[ii];
                cur -= (int)dir_mat[ii][cur];
            }
            // sorted labels + rank of tr[j] among sorted labels
            int lab[LL];
            for (int i2 = 0; i2 < LL; ++i2) lab[i2] = tr_s[i2];
            for (int a2 = 1; a2 < LL; ++a2) {
                int key = lab[a2]; int b2 = a2 - 1;
                while (b2 >= 0 && lab[b2] > key) { lab[b2 + 1] = lab[b2]; --b2; }
                lab[b2 + 1] = key;
            }
            for (int i2 = 0; i2 < LL; ++i2) labels_out[b * LL + i2] = lab[i2];
            for (int j2 = 0; j2 < LL; ++j2) {
                int r2 = 0;
                for (int l2 = 0; l2 < LL; ++l2) if (lab[l2] == tr_s[j2]) r2 = l2;
                rank_s[j2] = r2;
            }
        }
    }
    __syncthreads();
    // pse[t] = tr[#boundaries <= t]; rowmap[t] = rank (la row) of that tr index
    for (int t = tid; t < TT; t += 256) {
        int cnt = 0;
        for (int j = 0; j < NTR; ++j) cnt += (t >= bdy_s[j]) ? 1 : 0;
        pse[b * TT + t] = tr_s[cnt];
        rowmap[b * TT + t] = rank_s[cnt];
    }
}

// ---------------- Kernel 5: segment feature sums (oh @ fr), tile-scatter ----------------
__global__ __launch_bounds__(256) void k_la(const float* __restrict__ feat,
                                            const int* __restrict__ rowmap,
                                            float* __restrict__ la) {
    int b = blockIdx.y;
    int t0 = blockIdx.x * 32;
    int tid = threadIdx.x;
    const float* fr = feat + ((size_t)b * (CC + TT) + CC) * DD;
    __shared__ int rm[32];
    if (tid < 32) rm[tid] = rowmap[b * TT + t0 + tid];
    __syncthreads();
    float ax = 0.f, ay = 0.f;
    int cur = rm[0];
    for (int k = 0; k < 32; ++k) {
        int r = rm[k];
        if (r != cur) {   // block-uniform branch
            float* dst = la + ((size_t)b * LL + cur) * DD + tid * 2;
            atomicAdd(dst, ax);
            atomicAdd(dst + 1, ay);
            ax = 0.f; ay = 0.f; cur = r;
        }
        const float2* p = (const float2*)(fr + (size_t)(t0 + k) * DD);
        float2 v = p[tid];
        ax += v.x; ay += v.y;
    }
    float* dst = la + ((size_t)b * LL + cur) * DD + tid * 2;
    atomicAdd(dst, ax);
    atomicAdd(dst + 1, ay);
}

// ---------------- Kernel 6a: row norms (one wave per row) ----------------
// waves 0..63: la rows; waves 64..255: tok feat rows
__global__ __launch_bounds__(256) void k_norms(const float* __restrict__ feat,
                                               const float* __restrict__ la,
                                               float* __restrict__ nla,
                                               float* __restrict__ ntk) {
    int wid = (blockIdx.x * 256 + threadIdx.x) >> 6;
    int lane = threadIdx.x & 63;
    const float* rowp;
    if (wid < BB * LL) rowp = la + (size_t)wid * DD;
    else {
        int k = wid - BB * LL;
        int b = k / CC, c = k - (k / CC) * CC;
        rowp = feat + ((size_t)b * (CC + TT) + c) * DD;
    }
    const float4* p = (const float4*)rowp;
    float ss = 0.f;
    for (int j = lane; j < DD / 4; j += 64) {
        float4 v = p[j];
        ss += v.x * v.x + v.y * v.y + v.z * v.z + v.w * v.w;
    }
    ss = wave_reduce_sum(ss);
    if (lane == 0) {
        float nn = fmaxf(sqrtf(ss), 1e-12f);
        if (wid < BB * LL) nla[wid] = nn; else ntk[wid - BB * LL] = nn;
    }
}

// ---------------- Kernel 6b: glc per-(b,l) row: 48 dots + logsumexp ----------------
__global__ __launch_bounds__(256) void k_glc(const float* __restrict__ feat,
                                             const float* __restrict__ la,
                                             const float* __restrict__ nla,
                                             const float* __restrict__ ntk,
                                             const int* __restrict__ labels,
                                             float* __restrict__ terms) {
    int l = blockIdx.x, b = blockIdx.y;
    __shared__ float la_s[DD];
    __shared__ float sim_s[CC];
    int tid = threadIdx.x;
    const float* lar = la + ((size_t)b * LL + l) * DD;
    ((float2*)la_s)[tid] = ((const float2*)lar)[tid];
    __syncthreads();
    int wave = tid >> 6, lane = tid & 63;
    float inv_nla = 10.0f / nla[b * LL + l];      // *1/TEMP folded
    for (int c = wave; c < CC; c += 4) {
        const float4* tr = (const float4*)(feat + ((size_t)b * (CC + TT) + c) * DD);
        const float4* ls = (const float4*)la_s;
        float dot = 0.f;
        for (int j = lane; j < DD / 4; j += 64) {
            float4 a = ls[j]; float4 v = tr[j];
            dot += a.x * v.x + a.y * v.y + a.z * v.z + a.w * v.w;
        }
        dot = wave_reduce_sum(dot);
        if (lane == 0) sim_s[c] = dot * inv_nla / ntk[b * CC + c];
    }
    __syncthreads();
    if (tid == 0) {
        float mx = -INFINITY;
        for (int c = 0; c < CC; ++c) mx = fmaxf(mx, sim_s[c]);
        float se = 0.f;
        for (int c = 0; c < CC; ++c) se += expf(sim_s[c] - mx);
        int lab = labels[b * LL + l];
        terms[b * LL + l] = (mx + logf(se)) - sim_s[lab];
    }
}

// ---------------- Kernel 6c: fr CE partial sum ----------------
__global__ __launch_bounds__(256) void k_fr(const float* __restrict__ fr_logit,
                                            const float* __restrict__ lse,
                                            const int* __restrict__ pse,
                                            float* __restrict__ fr_acc) {
    int i = blockIdx.x * 256 + threadIdx.x;     // 32 blocks cover B*T=8192
    int p = pse[i];
    float v = lse[i] - fr_logit[(size_t)i * CC + p];
    v = wave_reduce_sum(v);
    if ((threadIdx.x & 63) == 0) atomicAdd(fr_acc, v);
}

// ---------------- Kernel 6d: combine ----------------
__global__ __launch_bounds__(256) void k_combine(const float* __restrict__ tok_logit,
                                                 const float* __restrict__ vid,
                                                 const float* __restrict__ fr_acc,
                                                 const float* __restrict__ terms,
                                                 float* __restrict__ out) {
    int tid = threadIdx.x;
    __shared__ float red[4];
    float acc = 0.f;
    if (tid < BB * CC) {
        float x = tok_logit[tid], y = vid[tid];
        float lsp = fminf(x, 0.f) - log1pf(expf(-fabsf(x)));
        float lsn = fminf(-x, 0.f) - log1pf(expf(-fabsf(x)));
        acc = -(y * lsp + (1.f - y) * lsn);
    }
    float w = wave_reduce_sum(acc);
    if ((tid & 63) == 0) red[tid >> 6] = w;
    __syncthreads();
    if (tid == 0) {
        float s_tok = (red[0] + red[1] + red[2] + red[3]) / (float)(BB * CC);
        float s_fr = fr_acc[0] / (float)(BB * TT);
        float g = 0.f;
        for (int i = 0; i < BB * LL; ++i) g += terms[i];
        float glc = g / (float)(BB * LL);
        out[0] = s_tok + s_fr + 0.1f * glc;
    }
}

extern "C" void kernel_launch(void* const* d_in, const int* in_sizes, int n_in,
                              void* d_out, int out_size, void* d_ws, size_t ws_size,
                              hipStream_t stream) {
    (void)in_sizes; (void)n_in; (void)out_size; (void)ws_size;
    // input order: epoch, tok_logit, fr_logit, mask, transcript, vid_multi_hot, feat
    const float* tok_logit  = (const float*)d_in[1];
    const float* fr_logit   = (const float*)d_in[2];
    const int*   transcript = (const int*)d_in[4];
    const float* vid        = (const float*)d_in[5];
    const float* feat       = (const float*)d_in[6];

    char* ws = (char*)d_ws;
    float* prob   = (float*)(ws + 0);          // B*T*C
    float* logp   = (float*)(ws + 1572864);    // B*T*C
    float* lse    = (float*)(ws + 3145728);    // B*T
    float* score  = (float*)(ws + 3178496);    // B*T
    float* la     = (float*)(ws + 3211264);    // B*L*D (131072 B)
    float* fr_acc = (float*)(ws + 3342336);    // 1 (zeroed with la)
    float* terms  = (float*)(ws + 3342592);    // B*L
    float* nla    = (float*)(ws + 3342848);    // B*L
    float* ntk    = (float*)(ws + 3343104);    // B*C
    int*   cand   = (int*)(ws + 3343872);      // B*64
    int*   labels = (int*)(ws + 3344896);      // B*L
    int*   pse    = (int*)(ws + 3345152);      // B*T
    int*   rowmap = (int*)(ws + 3377920);      // B*T
    float* out    = (float*)d_out;

    // zero la + fr_acc in one memset (contiguous region)
    hipMemsetAsync(la, 0, 131072 + 256, stream);

    k_softmax<<<BB * TT, 64, 0, stream>>>(fr_logit, prob, logp, lse);
    k_score<<<BB * TT, 64, 0, stream>>>(prob, logp, score);
    k_pick<<<BB, 64, 0, stream>>>(score, cand);
    k_dp<<<BB, 256, 0, stream>>>(prob, score, cand, transcript, labels, pse, rowmap);
    k_la<<<dim3(TT / 32, BB), 256, 0, stream>>>(feat, rowmap, la);
    k_norms<<<64, 256, 0, stream>>>(feat, la, nla, ntk);
    k_glc<<<dim3(LL, BB), 256, 0, stream>>>(feat, la, nla, ntk, labels, terms);
    k_fr<<<BB * TT / 256, 256, 0, stream>>>(fr_logit, lse, pse, fr_acc);
    k_combine<<<1, 256, 0, stream>>>(tok_logit, vid, fr_acc, terms, out);
}